// Round 3
// 1040.749 us; speedup vs baseline: 1.0257x; 1.0257x over previous
//
#include <hip/hip_runtime.h>

#define NTOT 100000
#define KMOD 6

typedef short bf16x8 __attribute__((ext_vector_type(8)));
typedef float f32x4  __attribute__((ext_vector_type(4)));
typedef unsigned short u16x8 __attribute__((ext_vector_type(8)));

// cst layout (float offsets)
#define G1   0
#define B1O  128
#define G2   256
#define B2O  384
#define W0A  512
#define W0B  640
#define B0O  768
#define DG1  896
#define DB1  1024
#define AGTG 1152
#define AGTB 1280
#define CG1  1408
#define CB1O 1536
#define CG2  1664
#define CB2O 1792
#define CWO  1920
#define PBO  2048

__device__ __forceinline__ unsigned short f2bf(float f){
  union { float f; unsigned u; } c; c.f = f;
  return (unsigned short)((c.u + 0x7FFFu + ((c.u >> 16) & 1u)) >> 16);
}
__device__ __forceinline__ float bf2f(unsigned short h){
  union { unsigned u; float f; } c; c.u = ((unsigned)h) << 16; return c.f;
}

// async global->LDS, 16B per lane; LDS dest must be (wave-uniform base + lane*16),
// which our linear t*16 layout satisfies.
__device__ __forceinline__ void gload16(const void* g, void* l){
  __builtin_amdgcn_global_load_lds(
      (const __attribute__((address_space(1))) unsigned int*)g,
      (__attribute__((address_space(3))) unsigned int*)l, 16, 0, 0);
}

// ---------------- weight prep: fp32 row-major -> bf16 MFMA fragment order ----------------
// flat[((ks*CB+cb)*64 + lane)*8 + j] = W[d = ks*32 + (lane>>4)*8 + j][c = cb*16 + (lane&15)]
__global__ void prep_w(const float* __restrict__ W1, const float* __restrict__ W2,
                       const float* __restrict__ Wo, const float* __restrict__ dW1,
                       const float* __restrict__ agW, const float* __restrict__ cW1,
                       const float* __restrict__ cW2, unsigned short* __restrict__ dst){
  int e = blockIdx.x * 256 + threadIdx.x;
  if (e >= 327680) return;
  const float* base; int m = 0, r, CB = 8, Dreal = 128, mstride = 16384;
  if (e < 98304)       { base = W1;  m = e / 16384; r = e % 16384; }
  else if (e < 196608) { int x = e - 98304;  base = W2; m = x / 16384; r = x % 16384; }
  else if (e < 245760) { int x = e - 196608; base = Wo; m = x / 8192;  r = x % 8192; CB = 4; Dreal = 60; mstride = 7680; }
  else if (e < 262144) { base = dW1; r = e - 245760; }
  else if (e < 294912) { base = agW; r = e - 262144; }
  else if (e < 311296) { base = cW1; r = e - 294912; }
  else                 { base = cW2; r = e - 311296; }
  int per = CB * 512;
  int ks = r / per, rr = r % per;
  int cb = rr >> 9, l = (rr >> 3) & 63, j = rr & 7;
  int d = ks * 32 + ((l >> 4) << 3) + j;
  int c = (cb << 4) + (l & 15);
  float v = (c < Dreal) ? base[(size_t)m * mstride + d * Dreal + c] : 0.f;
  dst[e] = f2bf(v);
}

// ---------------- fused K=128 GEMM, kstep-granularity ping-pong pipeline ----------------
// Wc is split into two CBN*1024-byte halves. For each kstep: issue next kstep's
// global_load_lds into the other half, counted s_waitcnt vmcnt(N) (never draining
// the in-flight prefetch), raw s_barrier, MFMA, lgkmcnt(0)+s_barrier to free the half.
template<int CBN>
__device__ __forceinline__ void gemm2(const char* __restrict__ wsrc,
                                      const unsigned short* __restrict__ Xin,
                                      unsigned short* __restrict__ Wc, f32x4* acc){
  const int t = threadIdx.x, lane = t & 63, w = t >> 6;
  constexpr int kbytes = CBN * 1024;        // bytes per kstep
  constexpr int nld = kbytes / 4096;        // 16B gload_lds per thread per kstep (2 or 1)
  char* wlds = (char*)Wc;
  // entry barrier: publish prior ds_writes (Xin / A0 / cst), prior Wc readers done
  asm volatile("s_waitcnt lgkmcnt(0)" ::: "memory");
  __builtin_amdgcn_s_barrier();
  asm volatile("" ::: "memory");
  // prologue: kstep 0 -> half 0
  #pragma unroll
  for (int i = 0; i < nld; ++i)
    gload16(wsrc + (t + i * 256) * 16, wlds + (t + i * 256) * 16);
  #pragma unroll
  for (int k = 0; k < 4; ++k){
    if (k < 3){
      const char* src = wsrc + (k + 1) * kbytes;
      char* dstp = wlds + ((k + 1) & 1) * kbytes;
      #pragma unroll
      for (int i = 0; i < nld; ++i)
        gload16(src + (t + i * 256) * 16, dstp + (t + i * 256) * 16);
      // oldest (all but the nld just-issued) must be done: kstep k's loads landed.
      if constexpr (nld == 2) asm volatile("s_waitcnt vmcnt(2)" ::: "memory");
      else                    asm volatile("s_waitcnt vmcnt(1)" ::: "memory");
    } else {
      asm volatile("s_waitcnt vmcnt(0)" ::: "memory");
    }
    __builtin_amdgcn_s_barrier();   // B1: kstep k weights visible in LDS
    asm volatile("" ::: "memory");
    bf16x8 a = *(const bf16x8*)(Xin + ((w * 4 + k) * 64 + lane) * 8);
    const unsigned short* wb = Wc + (k & 1) * CBN * 512 + lane * 8;
    #pragma unroll
    for (int cb = 0; cb < CBN; ++cb){
      bf16x8 b = *(const bf16x8*)(wb + cb * 512);
      acc[cb] = __builtin_amdgcn_mfma_f32_16x16x32_bf16(a, b, acc[cb], 0, 0, 0);
    }
    asm volatile("s_waitcnt lgkmcnt(0)" ::: "memory");  // our ds_reads retired
    __builtin_amdgcn_s_barrier();   // B2: half[k&1] free for next prefetch
    asm volatile("" ::: "memory");
  }
}

__device__ __forceinline__ void row_stats8(const f32x4* acc, float* mean, float* rstd){
  #pragma unroll
  for (int i = 0; i < 4; ++i){
    float s = 0.f, qq = 0.f;
    #pragma unroll
    for (int cb = 0; cb < 8; ++cb){ float v = acc[cb][i]; s += v; qq += v * v; }
    #pragma unroll
    for (int m = 1; m < 16; m <<= 1){ s += __shfl_xor(s, m, 16); qq += __shfl_xor(qq, m, 16); }
    float mu = s * 0.0078125f;
    float var = qq * 0.0078125f - mu * mu;
    mean[i] = mu; rstd[i] = rsqrtf(var + 1e-5f);
  }
}

// GN epilogue: normalize, optional bf16 residual gather, relu, optional feats store, store frag-order bf16
__device__ __forceinline__ void epi_gn(const f32x4* acc, const float* cst, int goff, int boff,
                                       const unsigned short* res, unsigned short* Xout,
                                       float* feats_out, int n0, int kk){
  const int t = threadIdx.x, lane = t & 63, w = t >> 6, q = lane >> 4, c0 = lane & 15;
  float mean[4], rstd[4];
  row_stats8(acc, mean, rstd);
  #pragma unroll
  for (int cb = 0; cb < 8; ++cb){
    int col = c0 + (cb << 4);
    float g = cst[goff + col], bb = cst[boff + col];
    int base = ((w * 4 + (col >> 5)) * 64 + ((col >> 3) & 3) * 16) * 8 + (col & 7);
    #pragma unroll
    for (int i = 0; i < 4; ++i){
      int r15 = (q << 2) + i;
      float v = (acc[cb][i] - mean[i]) * rstd[i] * g + bb;
      if (res) v += bf2f(res[base + r15 * 8]);
      v = fmaxf(v, 0.f);
      if (feats_out){
        int n = n0 + w * 16 + r15;
        if (n < NTOT)
          __builtin_nontemporal_store(v, &feats_out[(size_t)(n * KMOD + kk) * 128 + col]);
      }
      Xout[base + r15 * 8] = f2bf(v);
    }
  }
}

#define ZACC(a, n) { _Pragma("unroll") for (int z = 0; z < (n); ++z){ (a)[z][0]=0.f;(a)[z][1]=0.f;(a)[z][2]=0.f;(a)[z][3]=0.f; } }

// ---------------- mega fused kernel: 64 rows x 1 mode per block ----------------
__global__ __launch_bounds__(256, 2) void meg(
    const float* __restrict__ actors, const float* __restrict__ ctrs,
    const float* __restrict__ pg1, const float* __restrict__ pb1,
    const float* __restrict__ pg2, const float* __restrict__ pb2,
    const float* __restrict__ pbo, const float* __restrict__ dW0, const float* __restrict__ db0,
    const float* __restrict__ dg1, const float* __restrict__ db1v,
    const float* __restrict__ agg, const float* __restrict__ agb,
    const float* __restrict__ cg1v, const float* __restrict__ cb1v,
    const float* __restrict__ cg2v, const float* __restrict__ cb2v,
    const float* __restrict__ cWo, const float* __restrict__ cbo,
    const unsigned short* __restrict__ wprep, float* __restrict__ logits,
    float* __restrict__ out_reg, float* __restrict__ out_feats){

  __shared__ __align__(16) unsigned short A0[8192];
  __shared__ __align__(16) unsigned short X1[8192];
  __shared__ __align__(16) unsigned short X2[8192];
  __shared__ __align__(16) unsigned short Wc[8192];
  __shared__ float cst[2176];
  __shared__ float ctr_l[128];
  __shared__ float dist_l[128];

  const int t = threadIdx.x;
  const int kk = blockIdx.x % KMOD;
  const int tile = blockIdx.x / KMOD;
  const int n0 = tile * 64;
  const int valid = min(64, NTOT - n0);
  const float cbo_v = cbo[0];

  // ---- constants / ctrs into LDS ----
  if (t < 128){
    cst[G1 + t]   = pg1[kk * 128 + t];
    cst[B1O + t]  = pb1[kk * 128 + t];
    cst[G2 + t]   = pg2[kk * 128 + t];
    cst[B2O + t]  = pb2[kk * 128 + t];
    cst[W0A + t]  = dW0[t];
    cst[W0B + t]  = dW0[128 + t];
    cst[B0O + t]  = db0[t];
    cst[DG1 + t]  = dg1[t];
    cst[DB1 + t]  = db1v[t];
    cst[AGTG + t] = agg[t];
    cst[AGTB + t] = agb[t];
    cst[CG1 + t]  = cg1v[t];
    cst[CB1O + t] = cb1v[t];
    cst[CG2 + t]  = cg2v[t];
    cst[CB2O + t] = cb2v[t];
    cst[CWO + t]  = cWo[t];
  } else if (t < 192){
    int i = t - 128;
    cst[PBO + i] = (i < 60) ? pbo[kk * 60 + i] : 0.f;
  } else {
    int row = t - 192;
    if (row < valid){
      ctr_l[row * 2]     = ctrs[(size_t)(n0 + row) * 2];
      ctr_l[row * 2 + 1] = ctrs[(size_t)(n0 + row) * 2 + 1];
    } else { ctr_l[row * 2] = 0.f; ctr_l[row * 2 + 1] = 0.f; }
  }

  // ---- actors tile -> A0 (bf16, frag order) ----
  #pragma unroll
  for (int ii = 0; ii < 8; ++ii){
    int e2 = t + ii * 256;                 // 0..2047
    int row = e2 >> 5, c4 = e2 & 31;
    float4 v = make_float4(0.f, 0.f, 0.f, 0.f);
    if (row < valid) v = *(const float4*)(actors + (size_t)(n0 + row) * 128 + c4 * 4);
    int colb = c4 * 4;
    int idx = (((row >> 4) * 4 + (colb >> 5)) * 64 + (row & 15) + (((colb >> 3) & 3) << 4)) * 8 + (colb & 7);
    A0[idx]     = f2bf(v.x); A0[idx + 1] = f2bf(v.y);
    A0[idx + 2] = f2bf(v.z); A0[idx + 3] = f2bf(v.w);
  }

  const char* wp = (const char*)wprep;
  const char* W1k  = wp + (size_t)kk * 32768;
  const char* W2k  = wp + 196608 + (size_t)kk * 32768;
  const char* Wok  = wp + 393216 + (size_t)kk * 16384;
  const char* dW1p = wp + 491520;
  const char* agtp = wp + 524288;
  const char* cW1p = wp + 589824;
  const char* cW2p = wp + 622592;

  const int lane = t & 63, w = t >> 6, q = lane >> 4, c0 = lane & 15;
  f32x4 acc[8];

  // S1: h1 = relu(gn(A @ W1))           (gemm2 entry barrier publishes A0/cst)
  ZACC(acc, 8);
  gemm2<8>(W1k, A0, Wc, acc);
  epi_gn(acc, cst, G1, B1O, nullptr, X1, nullptr, n0, kk);

  // S2: h2 = relu(gn(h1 @ W2) + A)
  ZACC(acc, 8);
  gemm2<8>(W2k, X1, Wc, acc);
  epi_gn(acc, cst, G2, B2O, A0, X2, nullptr, n0, kk);

  // S3: preds = h2 @ Wo + bo ; reg = preds + ctr ; dist = -preds[:,58:60]
  {
    f32x4 acc4[4]; ZACC(acc4, 4);
    gemm2<4>(Wok, X2, Wc, acc4);
    #pragma unroll
    for (int cb = 0; cb < 4; ++cb){
      int col = c0 + (cb << 4);
      float bo = cst[PBO + col];
      #pragma unroll
      for (int i = 0; i < 4; ++i){
        int row = w * 16 + (q << 2) + i;
        float v = acc4[cb][i] + bo;
        if (col == 58) dist_l[row * 2]     = -v;
        if (col == 59) dist_l[row * 2 + 1] = -v;
        int n = n0 + row;
        if (col < 60 && n < NTOT)
          __builtin_nontemporal_store(v + ctr_l[row * 2 + (col & 1)],
                                      &out_reg[(size_t)(n * KMOD + kk) * 60 + col]);
      }
    }
  }
  __syncthreads();   // dist_l visible

  // S4: dh = relu(dist @ W0 + b0)  -> X1 (frag order, bf16)
  {
    int r15 = lane & 15;
    int row = w * 16 + r15;
    float d0 = dist_l[row * 2], d1 = dist_l[row * 2 + 1];
    #pragma unroll
    for (int ks = 0; ks < 4; ++ks){
      int dbase = ks * 32 + ((lane >> 4) << 3);
      u16x8 pack;
      #pragma unroll
      for (int j = 0; j < 8; ++j){
        int d = dbase + j;
        float v = fmaxf(d0 * cst[W0A + d] + d1 * cst[W0B + d] + cst[B0O + d], 0.f);
        pack[j] = f2bf(v);
      }
      *(u16x8*)(X1 + ((w * 4 + ks) * 64 + lane) * 8) = pack;
    }
  }

  // S5: dh2 = relu(gn(dh @ dist_W1))
  ZACC(acc, 8);
  gemm2<8>(dW1p, X1, Wc, acc);
  epi_gn(acc, cst, DG1, DB1, nullptr, X2, nullptr, n0, kk);

  // S6: feats = relu(gn([dh2, A] @ agt_W))  -> X1 + global feats
  ZACC(acc, 8);
  gemm2<8>(agtp, X2, Wc, acc);
  gemm2<8>(agtp + 32768, A0, Wc, acc);
  epi_gn(acc, cst, AGTG, AGTB, nullptr, X1, out_feats, n0, kk);

  // S7: c1 = relu(gn(feats @ cls_W1))
  ZACC(acc, 8);
  gemm2<8>(cW1p, X1, Wc, acc);
  epi_gn(acc, cst, CG1, CB1O, nullptr, X2, nullptr, n0, kk);

  // S8: c = relu(gn(c1 @ cls_W2) + feats); logit = c . cls_Wo + cls_bo
  ZACC(acc, 8);
  gemm2<8>(cW2p, X2, Wc, acc);
  {
    float mean[4], rstd[4];
    row_stats8(acc, mean, rstd);
    float part[4] = {0.f, 0.f, 0.f, 0.f};
    #pragma unroll
    for (int cb = 0; cb < 8; ++cb){
      int col = c0 + (cb << 4);
      float g = cst[CG2 + col], bb = cst[CB2O + col], wo = cst[CWO + col];
      int base = ((w * 4 + (col >> 5)) * 64 + ((col >> 3) & 3) * 16) * 8 + (col & 7);
      #pragma unroll
      for (int i = 0; i < 4; ++i){
        int r15 = (q << 2) + i;
        float v = (acc[cb][i] - mean[i]) * rstd[i] * g + bb;
        v += bf2f(X1[base + r15 * 8]);
        v = fmaxf(v, 0.f);
        part[i] += v * wo;
      }
    }
    #pragma unroll
    for (int i = 0; i < 4; ++i){
      #pragma unroll
      for (int m = 1; m < 16; m <<= 1) part[i] += __shfl_xor(part[i], m, 16);
    }
    if (c0 == 0){
      #pragma unroll
      for (int i = 0; i < 4; ++i){
        int n = n0 + w * 16 + (q << 2) + i;
        if (n < NTOT) logits[n * KMOD + kk] = part[i] + cbo_v;
      }
    }
  }
}

// ---------------- finalize: softmax + stable descending sort + in-place reg permute ----------------
__global__ __launch_bounds__(256) void fin(const float* __restrict__ logits,
                                           float* __restrict__ out_cls,
                                           float* __restrict__ out_reg){
  const int wid = blockIdx.x * 4 + (threadIdx.x >> 6);
  const int lane = threadIdx.x & 63;
  if (wid >= NTOT) return;
  const int n = wid;
  float lg[6];
  #pragma unroll
  for (int k2 = 0; k2 < 6; ++k2) lg[k2] = logits[n * 6 + k2];
  float mx = lg[0];
  #pragma unroll
  for (int k2 = 1; k2 < 6; ++k2) mx = fmaxf(mx, lg[k2]);
  float ex[6]; float s = 0.f;
  #pragma unroll
  for (int k2 = 0; k2 < 6; ++k2){ ex[k2] = expf(lg[k2] - mx); s += ex[k2]; }
  float inv = 1.f / s;
  int rank[6];
  #pragma unroll
  for (int k2 = 0; k2 < 6; ++k2){
    int r = 0;
    #pragma unroll
    for (int j2 = 0; j2 < 6; ++j2) r += (lg[j2] > lg[k2]) || (lg[j2] == lg[k2] && j2 < k2);
    rank[k2] = r;
  }
  if (lane < 6){
    float pv = 0.f;
    #pragma unroll
    for (int k2 = 0; k2 < 6; ++k2) pv += (rank[k2] == lane) ? ex[k2] : 0.f;
    out_cls[n * 6 + lane] = pv * inv;
  }
  if (lane < 60){
    float v[6];
    #pragma unroll
    for (int k2 = 0; k2 < 6; ++k2) v[k2] = out_reg[(size_t)(n * 6 + k2) * 60 + lane];
    #pragma unroll
    for (int r2 = 0; r2 < 6; ++r2){
      float ov = 0.f;
      #pragma unroll
      for (int k2 = 0; k2 < 6; ++k2) ov += (rank[k2] == r2) ? v[k2] : 0.f;
      out_reg[(size_t)(n * 6 + r2) * 60 + lane] = ov;
    }
  }
}

extern "C" void kernel_launch(void* const* d_in, const int* in_sizes, int n_in,
                              void* d_out, int out_size, void* d_ws, size_t ws_size,
                              hipStream_t stream){
  const float* actors = (const float*)d_in[0];
  const float* ctrs   = (const float*)d_in[1];
  const float* pW1 = (const float*)d_in[2];
  const float* pg1 = (const float*)d_in[3];
  const float* pb1 = (const float*)d_in[4];
  const float* pW2 = (const float*)d_in[5];
  const float* pg2 = (const float*)d_in[6];
  const float* pb2 = (const float*)d_in[7];
  const float* pWo = (const float*)d_in[8];
  const float* pbo = (const float*)d_in[9];
  const float* dW0 = (const float*)d_in[10];
  const float* db0 = (const float*)d_in[11];
  const float* dW1 = (const float*)d_in[12];
  const float* dg1 = (const float*)d_in[13];
  const float* db1 = (const float*)d_in[14];
  const float* agW = (const float*)d_in[15];
  const float* agg = (const float*)d_in[16];
  const float* agb = (const float*)d_in[17];
  const float* cW1 = (const float*)d_in[18];
  const float* cg1 = (const float*)d_in[19];
  const float* cb1 = (const float*)d_in[20];
  const float* cW2 = (const float*)d_in[21];
  const float* cg2 = (const float*)d_in[22];
  const float* cb2 = (const float*)d_in[23];
  const float* cWo = (const float*)d_in[24];
  const float* cbo = (const float*)d_in[25];

  float* logits = (float*)d_ws;                                     // 600000 floats
  unsigned short* wprep = (unsigned short*)((char*)d_ws + 2400256); // 655360 B (needs ws >= ~3.1 MB)
  float* out = (float*)d_out;
  float* out_cls   = out;               // [N,6]
  float* out_reg   = out + 600000;      // [N,6,30,2]
  float* out_feats = out + 36600000;    // [N*6,128]

  hipLaunchKernelGGL(prep_w, dim3(1280), dim3(256), 0, stream,
                     pW1, pW2, pWo, dW1, agW, cW1, cW2, wprep);
  hipLaunchKernelGGL(meg, dim3(((NTOT + 63) / 64) * KMOD), dim3(256), 0, stream,
                     actors, ctrs, pg1, pb1, pg2, pb2, pbo, dW0, db0, dg1, db1,
                     agg, agb, cg1, cb1, cg2, cb2, cWo, cbo, wprep, logits, out_reg, out_feats);
  hipLaunchKernelGGL(fin, dim3(NTOT / 4), dim3(256), 0, stream, logits, out_cls, out_reg);
}

// Round 5
// 985.096 us; speedup vs baseline: 1.0837x; 1.0565x over previous
//
#include <hip/hip_runtime.h>

#define NTOT 100000
#define KMOD 6

typedef short bf16x8 __attribute__((ext_vector_type(8)));
typedef float f32x4  __attribute__((ext_vector_type(4)));
typedef unsigned short u16x8 __attribute__((ext_vector_type(8)));
typedef unsigned short u16x4 __attribute__((ext_vector_type(4)));

__device__ __forceinline__ unsigned short f2bf(float f){
  union { float f; unsigned u; } c; c.f = f;
  return (unsigned short)((c.u + 0x7FFFu + ((c.u >> 16) & 1u)) >> 16);
}
__device__ __forceinline__ float bf2f(unsigned short h){
  union { unsigned u; float f; } c; c.u = ((unsigned)h) << 16; return c.f;
}

// ---------------- weight prep: fp32 row-major -> bf16 MFMA fragment order ----------------
// flat[((ks*CB+cb)*64 + lane)*8 + j] = W[d = ks*32 + (lane>>4)*8 + j][c = cb*16 + (lane&15)]
__global__ void prep_w(const float* __restrict__ W1, const float* __restrict__ W2,
                       const float* __restrict__ Wo, const float* __restrict__ dW1,
                       const float* __restrict__ agW, const float* __restrict__ cW1,
                       const float* __restrict__ cW2, unsigned short* __restrict__ dst){
  int e = blockIdx.x * 256 + threadIdx.x;
  if (e >= 327680) return;
  const float* base; int m = 0, r, CB = 8, Dreal = 128, mstride = 16384;
  if (e < 98304)       { base = W1;  m = e / 16384; r = e % 16384; }
  else if (e < 196608) { int x = e - 98304;  base = W2; m = x / 16384; r = x % 16384; }
  else if (e < 245760) { int x = e - 196608; base = Wo; m = x / 8192;  r = x % 8192; CB = 4; Dreal = 60; mstride = 7680; }
  else if (e < 262144) { base = dW1; r = e - 245760; }
  else if (e < 294912) { base = agW; r = e - 262144; }
  else if (e < 311296) { base = cW1; r = e - 294912; }
  else                 { base = cW2; r = e - 311296; }
  int per = CB * 512;
  int ks = r / per, rr = r % per;
  int cb = rr >> 9, l = (rr >> 3) & 63, j = rr & 7;
  int d = ks * 32 + ((l >> 4) << 3) + j;
  int c = (cb << 4) + (l & 15);
  float v = (c < Dreal) ? base[(size_t)m * mstride + d * Dreal + c] : 0.f;
  dst[e] = f2bf(v);
}

// ---------------- barrier-free K=128 GEMM: per-wave register B-fragments ----------------
// Wave-private: A-frags via ds_read_b128 from own quadrant; B-frags loaded directly
// from global (coalesced 16B/lane, L1/L2-hot weights), double-buffered in groups of 4.
// No LDS weight staging, no barriers.
template<int CBN>
__device__ __forceinline__ void gemmR(const char* __restrict__ wsrc,
                                      const unsigned short* __restrict__ Xin, f32x4* acc){
  const int t = threadIdx.x, lane = t & 63, w = t >> 6;
  bf16x8 a[4];
  #pragma unroll
  for (int ks = 0; ks < 4; ++ks)
    a[ks] = *(const bf16x8*)(Xin + ((w * 4 + ks) * 64 + lane) * 8);
  const char* wl = wsrc + lane * 16;
  bf16x8 bb[2][4];
  #pragma unroll
  for (int i = 0; i < 4; ++i)
    bb[0][i] = *(const bf16x8*)(wl + i * 1024);
  #pragma unroll
  for (int g = 0; g < CBN; ++g){          // CBN groups of 4 frags (total 4*CBN)
    if (g + 1 < CBN){
      #pragma unroll
      for (int i = 0; i < 4; ++i)
        bb[(g + 1) & 1][i] = *(const bf16x8*)(wl + ((g + 1) * 4 + i) * 1024);
    }
    #pragma unroll
    for (int i = 0; i < 4; ++i){
      const int fi = g * 4 + i;           // compile-time after unroll
      acc[fi % CBN] = __builtin_amdgcn_mfma_f32_16x16x32_bf16(
          a[fi / CBN], bb[g & 1][i], acc[fi % CBN], 0, 0, 0);
    }
  }
}

__device__ __forceinline__ void row_stats8(const f32x4* acc, float* mean, float* rstd){
  #pragma unroll
  for (int i = 0; i < 4; ++i){
    float s = 0.f, qq = 0.f;
    #pragma unroll
    for (int cb = 0; cb < 8; ++cb){ float v = acc[cb][i]; s += v; qq += v * v; }
    #pragma unroll
    for (int m = 1; m < 16; m <<= 1){ s += __shfl_xor(s, m, 16); qq += __shfl_xor(qq, m, 16); }
    float mu = s * 0.0078125f;
    float var = qq * 0.0078125f - mu * mu;
    mean[i] = mu; rstd[i] = rsqrtf(var + 1e-5f);
  }
}

// GN epilogue: gains/bias straight from global (L1-hot), optional bf16 residual,
// relu, optional feats store, store frag-order bf16 into own wave quadrant.
__device__ __forceinline__ void epi_gn(const f32x4* acc, const float* __restrict__ gptr,
                                       const float* __restrict__ bptr,
                                       const unsigned short* res, unsigned short* Xout,
                                       float* feats_out, int n0, int kk){
  const int t = threadIdx.x, lane = t & 63, w = t >> 6, q = lane >> 4, c0 = lane & 15;
  float mean[4], rstd[4];
  row_stats8(acc, mean, rstd);
  #pragma unroll
  for (int cb = 0; cb < 8; ++cb){
    int col = c0 + (cb << 4);
    float g = gptr[col], bb = bptr[col];
    int base = ((w * 4 + (col >> 5)) * 64 + ((col >> 3) & 3) * 16) * 8 + (col & 7);
    #pragma unroll
    for (int i = 0; i < 4; ++i){
      int r15 = (q << 2) + i;
      float v = (acc[cb][i] - mean[i]) * rstd[i] * g + bb;
      if (res) v += bf2f(res[base + r15 * 8]);
      v = fmaxf(v, 0.f);
      if (feats_out){
        int n = n0 + w * 16 + r15;
        if (n < NTOT) feats_out[(size_t)(n * KMOD + kk) * 128 + col] = v;
      }
      Xout[base + r15 * 8] = f2bf(v);
    }
  }
}

#define ZACC(a, n) { _Pragma("unroll") for (int z = 0; z < (n); ++z){ (a)[z][0]=0.f;(a)[z][1]=0.f;(a)[z][2]=0.f;(a)[z][3]=0.f; } }

// ---------------- mega fused kernel: 64 rows x 1 mode, ZERO barriers ----------------
// All LDS state is wave-private (wave w owns rows w*16..w*16+15); waves never sync.
__global__ __launch_bounds__(256, 2) void meg(
    const float* __restrict__ actors, const float* __restrict__ ctrs,
    const float* __restrict__ pg1, const float* __restrict__ pb1,
    const float* __restrict__ pg2, const float* __restrict__ pb2,
    const float* __restrict__ pbo, const float* __restrict__ dW0, const float* __restrict__ db0,
    const float* __restrict__ dg1, const float* __restrict__ db1v,
    const float* __restrict__ agg, const float* __restrict__ agb,
    const float* __restrict__ cg1v, const float* __restrict__ cb1v,
    const float* __restrict__ cg2v, const float* __restrict__ cb2v,
    const float* __restrict__ cWo, const float* __restrict__ cbo,
    const unsigned short* __restrict__ wprep, float* __restrict__ logits,
    float* __restrict__ out_reg, float* __restrict__ out_feats){

  __shared__ __align__(16) unsigned short A0[8192];
  __shared__ __align__(16) unsigned short X1[8192];
  __shared__ __align__(16) unsigned short X2[8192];
  __shared__ float ctr_l[128];
  __shared__ float dist_l[128];

  const int t = threadIdx.x, lane = t & 63, w = t >> 6;
  const int kk = blockIdx.x % KMOD;
  const int tile = blockIdx.x / KMOD;
  const int n0 = tile * 64;
  const int valid = min(64, NTOT - n0);
  const float cbo_v = cbo[0];

  // ---- ctr fill: wave-private rows ----
  if (lane < 32){
    int r = lane >> 1, which = lane & 1;
    int row = w * 16 + r;
    ctr_l[row * 2 + which] = (row < valid) ? ctrs[(size_t)(n0 + row) * 2 + which] : 0.f;
  }

  // ---- actors tile -> A0 (bf16, frag order), wave-private rows ----
  {
    int r15 = lane >> 2, cq = lane & 3;
    int row = w * 16 + r15;
    const float* arow = actors + (size_t)(n0 + row) * 128;
    #pragma unroll
    for (int ii = 0; ii < 8; ++ii){
      int c4 = cq * 8 + ii;                // 0..31
      float4 v = make_float4(0.f, 0.f, 0.f, 0.f);
      if (row < valid) v = *(const float4*)(arow + c4 * 4);
      int colb = c4 * 4;
      int idx = ((w * 4 + (colb >> 5)) * 64 + r15 + (((colb >> 3) & 3) << 4)) * 8 + (colb & 7);
      u16x4 p; p[0] = f2bf(v.x); p[1] = f2bf(v.y); p[2] = f2bf(v.z); p[3] = f2bf(v.w);
      *(u16x4*)(A0 + idx) = p;
    }
  }

  const char* wp = (const char*)wprep;
  const char* W1k  = wp + (size_t)kk * 32768;
  const char* W2k  = wp + 196608 + (size_t)kk * 32768;
  const char* Wok  = wp + 393216 + (size_t)kk * 16384;
  const char* dW1p = wp + 491520;
  const char* agtp = wp + 524288;
  const char* cW1p = wp + 589824;
  const char* cW2p = wp + 622592;

  const int q = lane >> 4, c0 = lane & 15;
  f32x4 acc[8];

  // S1: h1 = relu(gn(A @ W1))
  ZACC(acc, 8);
  gemmR<8>(W1k, A0, acc);
  epi_gn(acc, pg1 + kk * 128, pb1 + kk * 128, nullptr, X1, nullptr, n0, kk);

  // S2: h2 = relu(gn(h1 @ W2) + A)
  ZACC(acc, 8);
  gemmR<8>(W2k, X1, acc);
  epi_gn(acc, pg2 + kk * 128, pb2 + kk * 128, A0, X2, nullptr, n0, kk);

  // S3: preds = h2 @ Wo + bo ; reg = preds + ctr ; dist = -preds[:,58:60]
  {
    f32x4 acc4[4]; ZACC(acc4, 4);
    gemmR<4>(Wok, X2, acc4);
    #pragma unroll
    for (int cb = 0; cb < 4; ++cb){
      int col = c0 + (cb << 4);
      float bo = (col < 60) ? pbo[kk * 60 + col] : 0.f;
      #pragma unroll
      for (int i = 0; i < 4; ++i){
        int row = w * 16 + (q << 2) + i;
        float v = acc4[cb][i] + bo;
        if (col == 58) dist_l[row * 2]     = -v;
        if (col == 59) dist_l[row * 2 + 1] = -v;
        int n = n0 + row;
        if (col < 60 && n < NTOT)
          out_reg[(size_t)(n * KMOD + kk) * 60 + col] = v + ctr_l[row * 2 + (col & 1)];
      }
    }
  }
  // dist_l: written and read by the same wave; enforce LDS completion + no reordering
  asm volatile("s_waitcnt lgkmcnt(0)" ::: "memory");
  __builtin_amdgcn_sched_barrier(0);

  // S4: dh = relu(dist @ W0 + b0)  -> X1 (frag order, bf16)
  {
    int r15 = lane & 15;
    int row = w * 16 + r15;
    float d0 = dist_l[row * 2], d1 = dist_l[row * 2 + 1];
    #pragma unroll
    for (int ks = 0; ks < 4; ++ks){
      int dbase = ks * 32 + ((lane >> 4) << 3);
      float4 wa0 = *(const float4*)(dW0 + dbase);
      float4 wa1 = *(const float4*)(dW0 + dbase + 4);
      float4 wb0 = *(const float4*)(dW0 + 128 + dbase);
      float4 wb1 = *(const float4*)(dW0 + 128 + dbase + 4);
      float4 b00 = *(const float4*)(db0 + dbase);
      float4 b01 = *(const float4*)(db0 + dbase + 4);
      u16x8 pack;
      pack[0] = f2bf(fmaxf(d0 * wa0.x + d1 * wb0.x + b00.x, 0.f));
      pack[1] = f2bf(fmaxf(d0 * wa0.y + d1 * wb0.y + b00.y, 0.f));
      pack[2] = f2bf(fmaxf(d0 * wa0.z + d1 * wb0.z + b00.z, 0.f));
      pack[3] = f2bf(fmaxf(d0 * wa0.w + d1 * wb0.w + b00.w, 0.f));
      pack[4] = f2bf(fmaxf(d0 * wa1.x + d1 * wb1.x + b01.x, 0.f));
      pack[5] = f2bf(fmaxf(d0 * wa1.y + d1 * wb1.y + b01.y, 0.f));
      pack[6] = f2bf(fmaxf(d0 * wa1.z + d1 * wb1.z + b01.z, 0.f));
      pack[7] = f2bf(fmaxf(d0 * wa1.w + d1 * wb1.w + b01.w, 0.f));
      *(u16x8*)(X1 + ((w * 4 + ks) * 64 + lane) * 8) = pack;
    }
  }

  // S5: dh2 = relu(gn(dh @ dist_W1))
  ZACC(acc, 8);
  gemmR<8>(dW1p, X1, acc);
  epi_gn(acc, dg1, db1v, nullptr, X2, nullptr, n0, kk);

  // S6: feats = relu(gn([dh2, A] @ agt_W))  -> X1 + global feats
  ZACC(acc, 8);
  gemmR<8>(agtp, X2, acc);
  gemmR<8>(agtp + 32768, A0, acc);
  epi_gn(acc, agg, agb, nullptr, X1, out_feats, n0, kk);

  // S7: c1 = relu(gn(feats @ cls_W1))
  ZACC(acc, 8);
  gemmR<8>(cW1p, X1, acc);
  epi_gn(acc, cg1v, cb1v, nullptr, X2, nullptr, n0, kk);

  // S8: c = relu(gn(c1 @ cls_W2) + feats); logit = c . cls_Wo + cls_bo
  ZACC(acc, 8);
  gemmR<8>(cW2p, X2, acc);
  {
    float mean[4], rstd[4];
    row_stats8(acc, mean, rstd);
    float part[4] = {0.f, 0.f, 0.f, 0.f};
    #pragma unroll
    for (int cb = 0; cb < 8; ++cb){
      int col = c0 + (cb << 4);
      float g = cg2v[col], bb = cb2v[col], wo = cWo[col];
      int base = ((w * 4 + (col >> 5)) * 64 + ((col >> 3) & 3) * 16) * 8 + (col & 7);
      #pragma unroll
      for (int i = 0; i < 4; ++i){
        int r15 = (q << 2) + i;
        float v = (acc[cb][i] - mean[i]) * rstd[i] * g + bb;
        v += bf2f(X1[base + r15 * 8]);
        v = fmaxf(v, 0.f);
        part[i] += v * wo;
      }
    }
    #pragma unroll
    for (int i = 0; i < 4; ++i){
      #pragma unroll
      for (int m = 1; m < 16; m <<= 1) part[i] += __shfl_xor(part[i], m, 16);
    }
    if (c0 == 0){
      #pragma unroll
      for (int i = 0; i < 4; ++i){
        int n = n0 + w * 16 + (q << 2) + i;
        if (n < NTOT) logits[n * KMOD + kk] = part[i] + cbo_v;
      }
    }
  }
}

// ---------------- finalize: softmax + stable descending sort + in-place reg permute ----------------
__global__ __launch_bounds__(256) void fin(const float* __restrict__ logits,
                                           float* __restrict__ out_cls,
                                           float* __restrict__ out_reg){
  const int wid = blockIdx.x * 4 + (threadIdx.x >> 6);
  const int lane = threadIdx.x & 63;
  if (wid >= NTOT) return;
  const int n = wid;
  float lg[6];
  #pragma unroll
  for (int k2 = 0; k2 < 6; ++k2) lg[k2] = logits[n * 6 + k2];
  float mx = lg[0];
  #pragma unroll
  for (int k2 = 1; k2 < 6; ++k2) mx = fmaxf(mx, lg[k2]);
  float ex[6]; float s = 0.f;
  #pragma unroll
  for (int k2 = 0; k2 < 6; ++k2){ ex[k2] = expf(lg[k2] - mx); s += ex[k2]; }
  float inv = 1.f / s;
  int rank[6];
  #pragma unroll
  for (int k2 = 0; k2 < 6; ++k2){
    int r = 0;
    #pragma unroll
    for (int j2 = 0; j2 < 6; ++j2) r += (lg[j2] > lg[k2]) || (lg[j2] == lg[k2] && j2 < k2);
    rank[k2] = r;
  }
  if (lane < 6){
    float pv = 0.f;
    #pragma unroll
    for (int k2 = 0; k2 < 6; ++k2) pv += (rank[k2] == lane) ? ex[k2] : 0.f;
    out_cls[n * 6 + lane] = pv * inv;
  }
  if (lane < 60){
    float v[6];
    #pragma unroll
    for (int k2 = 0; k2 < 6; ++k2) v[k2] = out_reg[(size_t)(n * 6 + k2) * 60 + lane];
    #pragma unroll
    for (int r2 = 0; r2 < 6; ++r2){
      float ov = 0.f;
      #pragma unroll
      for (int k2 = 0; k2 < 6; ++k2) ov += (rank[k2] == r2) ? v[k2] : 0.f;
      out_reg[(size_t)(n * 6 + r2) * 60 + lane] = ov;
    }
  }
}

extern "C" void kernel_launch(void* const* d_in, const int* in_sizes, int n_in,
                              void* d_out, int out_size, void* d_ws, size_t ws_size,
                              hipStream_t stream){
  const float* actors = (const float*)d_in[0];
  const float* ctrs   = (const float*)d_in[1];
  const float* pW1 = (const float*)d_in[2];
  const float* pg1 = (const float*)d_in[3];
  const float* pb1 = (const float*)d_in[4];
  const float* pW2 = (const float*)d_in[5];
  const float* pg2 = (const float*)d_in[6];
  const float* pb2 = (const float*)d_in[7];
  const float* pWo = (const float*)d_in[8];
  const float* pbo = (const float*)d_in[9];
  const float* dW0 = (const float*)d_in[10];
  const float* db0 = (const float*)d_in[11];
  const float* dW1 = (const float*)d_in[12];
  const float* dg1 = (const float*)d_in[13];
  const float* db1 = (const float*)d_in[14];
  const float* agW = (const float*)d_in[15];
  const float* agg = (const float*)d_in[16];
  const float* agb = (const float*)d_in[17];
  const float* cW1 = (const float*)d_in[18];
  const float* cg1 = (const float*)d_in[19];
  const float* cb1 = (const float*)d_in[20];
  const float* cW2 = (const float*)d_in[21];
  const float* cg2 = (const float*)d_in[22];
  const float* cb2 = (const float*)d_in[23];
  const float* cWo = (const float*)d_in[24];
  const float* cbo = (const float*)d_in[25];

  float* logits = (float*)d_ws;                                     // 600000 floats
  unsigned short* wprep = (unsigned short*)((char*)d_ws + 2400256); // 655360 B (needs ws >= ~3.1 MB)
  float* out = (float*)d_out;
  float* out_cls   = out;               // [N,6]
  float* out_reg   = out + 600000;      // [N,6,30,2]
  float* out_feats = out + 36600000;    // [N*6,128]

  hipLaunchKernelGGL(prep_w, dim3(1280), dim3(256), 0, stream,
                     pW1, pW2, pWo, dW1, agW, cW1, cW2, wprep);
  hipLaunchKernelGGL(meg, dim3(((NTOT + 63) / 64) * KMOD), dim3(256), 0, stream,
                     actors, ctrs, pg1, pb1, pg2, pb2, pbo, dW0, db0, dg1, db1,
                     agg, agb, cg1, cb1, cg2, cb2, cWo, cbo, wprep, logits, out_reg, out_feats);
  hipLaunchKernelGGL(fin, dim3(NTOT / 4), dim3(256), 0, stream, logits, out_cls, out_reg);
}